// Round 2
// baseline (41330.795 us; speedup 1.0000x reference)
//
#include <hip/hip_runtime.h>
#include <math.h>

// Problem dims
#define BB 32
#define TT 512
#define CC 256
#define DD 1024
#define HH_ 16
#define LL 6
#define FFD 4096
#define OO 256
#define QQ 8
#define KK 1024
#define NTOK (BB*TT)   // 16384

enum GemmMode { MODE_STORE=0, MODE_GELU=1, MODE_ADD=2 };

__device__ __forceinline__ float gelu_f(float x){
  return 0.5f * x * (1.0f + erff(x * 0.70710678118654752f));
}

// ---------------- generic fp32 GEMM: C = op(A[MxK] @ W[KxN] + bias) ----------------
// 128x128 tile, BK=16, 256 threads, 8x8 microtile (split as 2x 4-row / 4-col chunks
// 64 apart to keep LDS b128 reads 2-way-or-less banked).
template<int MODE>
__global__ __launch_bounds__(256) void gemm_k(
    const float* __restrict__ A, const float* __restrict__ W,
    const float* __restrict__ bias, float* __restrict__ C,
    int M, int N, int K)
{
  __shared__ float As[16][132];   // [k][m], padded
  __shared__ float Ws[16][132];   // [k][n], padded
  const int tid = threadIdx.x;
  const int tx = tid & 15;
  const int ty = tid >> 4;
  const int m0 = blockIdx.y * 128;
  const int n0 = blockIdx.x * 128;
  const int arow = tid >> 1;
  const int acol = (tid & 1) * 8;
  const int wrow = tid >> 4;
  const int wcol = (tid & 15) * 8;
  const bool arow_ok = (m0 + arow) < M;

  float acc[8][8] = {};

  for (int k0 = 0; k0 < K; k0 += 16) {
    float4 av0 = make_float4(0.f,0.f,0.f,0.f), av1 = av0;
    if (arow_ok) {
      const float* ap = A + (size_t)(m0 + arow) * K + (k0 + acol);
      av0 = *(const float4*)(ap);
      av1 = *(const float4*)(ap + 4);
    }
    const float* wp = W + (size_t)(k0 + wrow) * N + (n0 + wcol);
    float4 wv0 = *(const float4*)(wp);
    float4 wv1 = *(const float4*)(wp + 4);
    __syncthreads();
    As[acol+0][arow] = av0.x; As[acol+1][arow] = av0.y;
    As[acol+2][arow] = av0.z; As[acol+3][arow] = av0.w;
    As[acol+4][arow] = av1.x; As[acol+5][arow] = av1.y;
    As[acol+6][arow] = av1.z; As[acol+7][arow] = av1.w;
    *(float4*)&Ws[wrow][wcol]   = wv0;
    *(float4*)&Ws[wrow][wcol+4] = wv1;
    __syncthreads();
    #pragma unroll
    for (int k = 0; k < 16; ++k) {
      float4 a0 = *(const float4*)&As[k][ty*4];
      float4 a1 = *(const float4*)&As[k][ty*4 + 64];
      float4 b0 = *(const float4*)&Ws[k][tx*4];
      float4 b1 = *(const float4*)&Ws[k][tx*4 + 64];
      float ar[8] = {a0.x,a0.y,a0.z,a0.w,a1.x,a1.y,a1.z,a1.w};
      float br[8] = {b0.x,b0.y,b0.z,b0.w,b1.x,b1.y,b1.z,b1.w};
      #pragma unroll
      for (int i = 0; i < 8; ++i)
        #pragma unroll
        for (int j = 0; j < 8; ++j)
          acc[i][j] = fmaf(ar[i], br[j], acc[i][j]);
    }
  }

  #pragma unroll
  for (int ih = 0; ih < 2; ++ih) {
    #pragma unroll
    for (int i = 0; i < 4; ++i) {
      const int m = m0 + ih*64 + ty*4 + i;
      if (m >= M) continue;
      #pragma unroll
      for (int jh = 0; jh < 2; ++jh) {
        const int n = n0 + jh*64 + tx*4;
        float4 bs = *(const float4*)&bias[n];
        float r0 = acc[ih*4+i][jh*4+0] + bs.x;
        float r1 = acc[ih*4+i][jh*4+1] + bs.y;
        float r2 = acc[ih*4+i][jh*4+2] + bs.z;
        float r3 = acc[ih*4+i][jh*4+3] + bs.w;
        if (MODE == MODE_GELU) { r0=gelu_f(r0); r1=gelu_f(r1); r2=gelu_f(r2); r3=gelu_f(r3); }
        float* p = C + (size_t)m * N + n;
        if (MODE == MODE_ADD) {
          float4 old = *(const float4*)p;
          r0 += old.x; r1 += old.y; r2 += old.z; r3 += old.w;
        }
        *(float4*)p = make_float4(r0,r1,r2,r3);
      }
    }
  }
}

// ---------------- LayerNorm: one block per row, D=1024, 256 threads ----------------
__global__ __launch_bounds__(256) void ln_k(
    const float* __restrict__ X, size_t xstride, float* __restrict__ Y,
    const float* __restrict__ g, const float* __restrict__ b)
{
  const int row = blockIdx.x;
  const int t = threadIdx.x;
  const float* x = X + (size_t)row * xstride;
  float* y = Y + (size_t)row * DD;
  __shared__ float red[4];
  float4 v = ((const float4*)x)[t];
  float s = v.x + v.y + v.z + v.w;
  #pragma unroll
  for (int o = 32; o > 0; o >>= 1) s += __shfl_down(s, o);
  const int wave = t >> 6, lane = t & 63;
  if (lane == 0) red[wave] = s;
  __syncthreads();
  const float mean = (red[0]+red[1]+red[2]+red[3]) * (1.0f/1024.0f);
  float4 d;
  d.x = v.x - mean; d.y = v.y - mean; d.z = v.z - mean; d.w = v.w - mean;
  float ss = d.x*d.x + d.y*d.y + d.z*d.z + d.w*d.w;
  __syncthreads();
  #pragma unroll
  for (int o = 32; o > 0; o >>= 1) ss += __shfl_down(ss, o);
  if (lane == 0) red[wave] = ss;
  __syncthreads();
  const float var = (red[0]+red[1]+red[2]+red[3]) * (1.0f/1024.0f);
  const float inv = rsqrtf(var + 1e-5f);
  float4 gg = ((const float4*)g)[t];
  float4 bb = ((const float4*)b)[t];
  float4 o4;
  o4.x = d.x * inv * gg.x + bb.x;
  o4.y = d.y * inv * gg.y + bb.y;
  o4.z = d.z * inv * gg.z + bb.z;
  o4.w = d.w * inv * gg.w + bb.w;
  ((float4*)y)[t] = o4;
}

// ---------------- h += pos (broadcast over batch) ----------------
__global__ __launch_bounds__(256) void addpos_k(float* __restrict__ H, const float* __restrict__ pos)
{
  const size_t i = (size_t)blockIdx.x * 256 + threadIdx.x;  // float4 index
  float4 v = ((const float4*)H)[i];
  const size_t row = i >> 8;             // 256 float4s per row
  const int tt = (int)(row & (TT-1));
  float4 p = ((const float4*)pos)[(size_t)tt * 256 + (i & 255)];
  v.x += p.x; v.y += p.y; v.z += p.z; v.w += p.w;
  ((float4*)H)[i] = v;
}

// ---------------- causal attention, flash-style ----------------
// grid (T/64, nb*H); block 256 = 64 q-rows x 4 groups. Each thread owns 16 keys
// (k = g + 4j) of each 64-key tile and a full 64-dim partial O accumulator;
// final 4-lane shuffle reduce. b index is relative to the chunk base passed in.
__global__ __launch_bounds__(256) void attn_k(
    const float* __restrict__ QKV, float* __restrict__ Oout)
{
  const int qt = blockIdx.x;       // 0..7
  const int bh = blockIdx.y;
  const int b  = bh >> 4;
  const int hh = bh & 15;
  const int tid = threadIdx.x;
  const int r = tid >> 2;          // q-row within tile
  const int g = tid & 3;           // key-group
  __shared__ float Qs[64][68];
  __shared__ float Ks[64][68];
  __shared__ float Vs[64][68];

  // stage Q tile
  {
    const int i = tid >> 2;
    const int c = (tid & 3) * 16;
    const float* qp = QKV + (size_t)(b*TT + qt*64 + i) * 3072 + hh*64 + c;
    #pragma unroll
    for (int j = 0; j < 16; j += 4)
      *(float4*)&Qs[i][c+j] = *(const float4*)(qp + j);
  }

  float o[64];
  #pragma unroll
  for (int d = 0; d < 64; ++d) o[d] = 0.0f;
  float mrow = -1e30f, lrow = 0.0f;
  const int q_global = qt*64 + r;
  const float scale = 0.125f;   // 1/sqrt(64)

  for (int kt = 0; kt <= qt; ++kt) {
    __syncthreads();
    {
      const int i = tid >> 2;
      const int c = (tid & 3) * 16;
      const float* kp = QKV + (size_t)(b*TT + kt*64 + i) * 3072 + 1024 + hh*64 + c;
      const float* vp = kp + 1024;
      #pragma unroll
      for (int j = 0; j < 16; j += 4) {
        *(float4*)&Ks[i][c+j] = *(const float4*)(kp + j);
        *(float4*)&Vs[i][c+j] = *(const float4*)(vp + j);
      }
    }
    __syncthreads();

    float s[16];
    #pragma unroll
    for (int j = 0; j < 16; ++j) s[j] = 0.0f;
    #pragma unroll
    for (int d0 = 0; d0 < 64; d0 += 4) {
      float4 q4 = *(const float4*)&Qs[r][d0];
      #pragma unroll
      for (int j = 0; j < 16; ++j) {
        float4 k4 = *(const float4*)&Ks[g + 4*j][d0];
        s[j] = fmaf(q4.x,k4.x, fmaf(q4.y,k4.y, fmaf(q4.z,k4.z, fmaf(q4.w,k4.w, s[j]))));
      }
    }
    float tmax = -1e30f;
    #pragma unroll
    for (int j = 0; j < 16; ++j) {
      const int kg = kt*64 + g + 4*j;
      s[j] = (kg <= q_global) ? s[j]*scale : -1e30f;
      tmax = fmaxf(tmax, s[j]);
    }
    tmax = fmaxf(tmax, __shfl_xor(tmax, 1));
    tmax = fmaxf(tmax, __shfl_xor(tmax, 2));
    const float mnew = fmaxf(mrow, tmax);
    const float alpha = expf(mrow - mnew);
    float p[16];
    float psum = 0.0f;
    #pragma unroll
    for (int j = 0; j < 16; ++j) { p[j] = expf(s[j] - mnew); psum += p[j]; }
    psum += __shfl_xor(psum, 1);
    psum += __shfl_xor(psum, 2);
    lrow = lrow * alpha + psum;
    #pragma unroll
    for (int d = 0; d < 64; ++d) o[d] *= alpha;
    #pragma unroll
    for (int j = 0; j < 16; ++j) {
      const float pj = p[j];
      #pragma unroll
      for (int d0 = 0; d0 < 64; d0 += 4) {
        float4 v4 = *(const float4*)&Vs[g + 4*j][d0];
        o[d0+0] = fmaf(pj, v4.x, o[d0+0]);
        o[d0+1] = fmaf(pj, v4.y, o[d0+1]);
        o[d0+2] = fmaf(pj, v4.z, o[d0+2]);
        o[d0+3] = fmaf(pj, v4.w, o[d0+3]);
      }
    }
    mrow = mnew;
  }

  #pragma unroll
  for (int d = 0; d < 64; ++d) {
    o[d] += __shfl_xor(o[d], 1);
    o[d] += __shfl_xor(o[d], 2);
  }
  const float invl = 1.0f / lrow;
  float* dst = Oout + (size_t)(b*TT + q_global) * DD + hh*64 + g*16;
  #pragma unroll
  for (int j = 0; j < 16; j += 4) {
    float4 w;
    w.x = o[g*16 + j + 0] * invl;
    w.y = o[g*16 + j + 1] * invl;
    w.z = o[g*16 + j + 2] * invl;
    w.w = o[g*16 + j + 3] * invl;
    *(float4*)(dst + j) = w;
  }
}

// ---------------- residual VQ: one block per batch row ----------------
__global__ __launch_bounds__(256) void rvq_k(
    const float* __restrict__ Z, const float* __restrict__ CB,
    const float* __restrict__ LS, float* __restrict__ OUT)
{
  const int b = blockIdx.x;
  const int t = threadIdx.x;
  __shared__ float rr[256];
  __shared__ float sred[256];
  __shared__ int   sidx[256];
  rr[t] = Z[b*OO + t];
  float acc = 0.0f;
  __syncthreads();
  for (int i = 0; i < QQ; ++i) {
    {
      const float x = rr[t];
      sred[t] = x * x;
    }
    __syncthreads();
    for (int s = 128; s > 0; s >>= 1) {
      if (t < s) sred[t] += sred[t + s];
      __syncthreads();
    }
    const float rsq = sred[0];
    __syncthreads();

    const float* cb = CB + (size_t)i * KK * OO;
    float best = 3.0e38f;
    int bj = 0;
    for (int j0 = 0; j0 < KK; j0 += 256) {
      const int j = j0 + t;
      const float* e = cb + (size_t)j * OO;
      float esq = 0.0f, dot = 0.0f;
      #pragma unroll 4
      for (int o = 0; o < OO; o += 4) {
        float4 e4 = *(const float4*)(e + o);
        esq = fmaf(e4.x,e4.x, fmaf(e4.y,e4.y, fmaf(e4.z,e4.z, fmaf(e4.w,e4.w, esq))));
        dot = fmaf(rr[o],e4.x, fmaf(rr[o+1],e4.y, fmaf(rr[o+2],e4.z, fmaf(rr[o+3],e4.w, dot))));
      }
      const float d = rsq + esq - 2.0f*dot;
      if (d < best) { best = d; bj = j; }   // ascending j -> first-min kept
    }
    sred[t] = best; sidx[t] = bj;
    __syncthreads();
    for (int s = 128; s > 0; s >>= 1) {
      if (t < s) {
        const float d2 = sred[t+s]; const int i2 = sidx[t+s];
        if (d2 < sred[t] || (d2 == sred[t] && i2 < sidx[t])) { sred[t] = d2; sidx[t] = i2; }
      }
      __syncthreads();
    }
    const int bestj = sidx[0];
    __syncthreads();
    const float zq  = cb[(size_t)bestj * OO + t];
    const float ls  = LS[i];
    const float sig = 1.0f / (1.0f + expf(-ls));
    acc = fmaf(sig, zq, acc);
    rr[t] -= zq;
    __syncthreads();
  }
  OUT[b*OO + t] = acc;
}

// ---------------- host launch ----------------
extern "C" void kernel_launch(void* const* d_in, const int* in_sizes, int n_in,
                              void* d_out, int out_size, void* d_ws, size_t ws_size,
                              hipStream_t stream) {
  const float* x       = (const float*)d_in[0];
  const float* w_in    = (const float*)d_in[1];
  const float* b_in    = (const float*)d_in[2];
  const float* pos     = (const float*)d_in[3];
  const float* ln1_g   = (const float*)d_in[4];
  const float* ln1_b   = (const float*)d_in[5];
  const float* qkv_w   = (const float*)d_in[6];
  const float* qkv_b   = (const float*)d_in[7];
  const float* proj_w  = (const float*)d_in[8];
  const float* proj_b  = (const float*)d_in[9];
  const float* ln2_g   = (const float*)d_in[10];
  const float* ln2_b   = (const float*)d_in[11];
  const float* ff1_w   = (const float*)d_in[12];
  const float* ff1_b   = (const float*)d_in[13];
  const float* ff2_w   = (const float*)d_in[14];
  const float* ff2_b   = (const float*)d_in[15];
  const float* lnf_g   = (const float*)d_in[16];
  const float* lnf_b   = (const float*)d_in[17];
  const float* out1_w  = (const float*)d_in[18];
  const float* out1_b  = (const float*)d_in[19];
  const float* out2_w  = (const float*)d_in[20];
  const float* out2_b  = (const float*)d_in[21];
  const float* codebooks    = (const float*)d_in[22];
  const float* layer_scales = (const float*)d_in[23];

  float* ws  = (float*)d_ws;

  // Adaptive workspace layout: base buffers first, `big` gets the remainder.
  float* h   = ws;                                   // 16384 x 1024  (64 MB)
  float* a   = h  + (size_t)NTOK * DD;               // 16384 x 1024  (64 MB)
  float* hl  = a  + (size_t)NTOK * DD;               // 32 x 1024
  float* z1  = hl + (size_t)BB * DD;                 // 32 x 1024
  float* zz  = z1 + (size_t)BB * DD;                 // 32 x 256
  float* big = zz + (size_t)BB * OO;                 // remainder

  const size_t avail_f = ws_size / sizeof(float);
  const size_t base_f  = (size_t)(big - ws);
  const size_t big_f   = (avail_f > base_f) ? (avail_f - base_f) : 0;

  // qkv chunk: batches per chunk (each batch needs T*3D floats in `big`)
  int nbc = (int)(big_f / ((size_t)TT * 3 * DD));
  if (nbc < 1) nbc = 1;
  if (nbc > BB) nbc = BB;
  // ff chunk: rows per chunk (each row needs FFD floats), multiple of 128
  int mc = (int)((big_f / FFD) / 128) * 128;
  if (mc < 128) mc = 128;
  if (mc > NTOK) mc = NTOK;

  const dim3 blk(256);

  // h = x @ w_in + b_in; h += pos
  gemm_k<MODE_STORE><<<dim3(DD/128, NTOK/128), blk, 0, stream>>>(x, w_in, b_in, h, NTOK, DD, CC);
  addpos_k<<<NTOK, blk, 0, stream>>>(h, pos);

  for (int l = 0; l < LL; ++l) {
    ln_k<<<NTOK, blk, 0, stream>>>(h, DD, a, ln1_g + l*DD, ln1_b + l*DD);
    for (int b0 = 0; b0 < BB; b0 += nbc) {
      const int nb = (b0 + nbc <= BB) ? nbc : (BB - b0);
      const int Mq = nb * TT;
      gemm_k<MODE_STORE><<<dim3((3*DD)/128, Mq/128), blk, 0, stream>>>(
          a + (size_t)b0*TT*DD, qkv_w + (size_t)l*DD*3*DD, qkv_b + (size_t)l*3*DD,
          big, Mq, 3*DD, DD);
      attn_k<<<dim3(TT/64, nb*HH_), blk, 0, stream>>>(big, a + (size_t)b0*TT*DD);
    }
    gemm_k<MODE_ADD><<<dim3(DD/128, NTOK/128), blk, 0, stream>>>(
        a, proj_w + (size_t)l*DD*DD, proj_b + (size_t)l*DD, h, NTOK, DD, DD);
    ln_k<<<NTOK, blk, 0, stream>>>(h, DD, a, ln2_g + l*DD, ln2_b + l*DD);
    for (int r0 = 0; r0 < NTOK; r0 += mc) {
      const int mr = (r0 + mc <= NTOK) ? mc : (NTOK - r0);
      gemm_k<MODE_GELU><<<dim3(FFD/128, mr/128), blk, 0, stream>>>(
          a + (size_t)r0*DD, ff1_w + (size_t)l*DD*FFD, ff1_b + (size_t)l*FFD,
          big, mr, FFD, DD);
      gemm_k<MODE_ADD><<<dim3(DD/128, mr/128), blk, 0, stream>>>(
          big, ff2_w + (size_t)l*FFD*DD, ff2_b + (size_t)l*DD, h + (size_t)r0*DD, mr, DD, FFD);
    }
  }

  // final LN on last token of each batch only
  ln_k<<<BB, blk, 0, stream>>>(h + (size_t)(TT-1)*DD, (size_t)TT*DD, hl, lnf_g, lnf_b);
  // head
  gemm_k<MODE_GELU><<<dim3(DD/128, 1), blk, 0, stream>>>(hl, out1_w, out1_b, z1, BB, DD, DD);
  gemm_k<MODE_STORE><<<dim3(OO/128, 1), blk, 0, stream>>>(z1, out2_w, out2_b, zz, BB, OO, DD);
  // residual VQ -> d_out
  rvq_k<<<BB, blk, 0, stream>>>(zz, codebooks, layer_scales, (float*)d_out);
}

// Round 3
// 18720.869 us; speedup vs baseline: 2.2077x; 2.2077x over previous
//
#include <hip/hip_runtime.h>
#include <math.h>

// Problem dims
#define BB 32
#define TT 512
#define CC 256
#define DD 1024
#define HH_ 16
#define LL 6
#define FFD 4096
#define OO 256
#define QQ 8
#define KK 1024
#define NTOK (BB*TT)   // 16384

enum GemmMode { MODE_STORE=0, MODE_GELU=1, MODE_ADD=2 };
enum { GM_STORE=0, GM_GELU_SPLIT=1, GM_ADD=2 };

typedef short bf16x8 __attribute__((ext_vector_type(8)));
typedef float f32x4_t __attribute__((ext_vector_type(4)));
typedef const __attribute__((address_space(1))) void gconst_t;
typedef __attribute__((address_space(3))) void ldsvoid_t;

__device__ __forceinline__ float gelu_f(float x){
  return 0.5f * x * (1.0f + erff(x * 0.70710678118654752f));
}

// bf16 bit helpers (RNE), avoid __hip_bfloat16 ABI entirely
__device__ __forceinline__ unsigned short f2bf(float x){
  unsigned int u = __float_as_uint(x);
  unsigned int r = (u + 0x7fffu + ((u >> 16) & 1u)) >> 16;
  return (unsigned short)r;
}
__device__ __forceinline__ float bf2f(unsigned short b){
  return __uint_as_float(((unsigned int)b) << 16);
}
__device__ __forceinline__ void split_store4(unsigned short* ph, unsigned short* pl,
                                             float a, float b, float c, float d){
  union { unsigned short s[4]; uint2 u; } th, tl;
  th.s[0]=f2bf(a); tl.s[0]=f2bf(a - bf2f(th.s[0]));
  th.s[1]=f2bf(b); tl.s[1]=f2bf(b - bf2f(th.s[1]));
  th.s[2]=f2bf(c); tl.s[2]=f2bf(c - bf2f(th.s[2]));
  th.s[3]=f2bf(d); tl.s[3]=f2bf(d - bf2f(th.s[3]));
  *(uint2*)ph = th.u; *(uint2*)pl = tl.u;
}

// ---------------- fp32 GEMM (kept for in-proj, head, and fallback path) ----------------
template<int MODE>
__global__ __launch_bounds__(256) void gemm_k(
    const float* __restrict__ A, const float* __restrict__ W,
    const float* __restrict__ bias, float* __restrict__ C,
    int M, int N, int K)
{
  __shared__ float As[16][132];
  __shared__ float Ws[16][132];
  const int tid = threadIdx.x;
  const int tx = tid & 15;
  const int ty = tid >> 4;
  const int m0 = blockIdx.y * 128;
  const int n0 = blockIdx.x * 128;
  const int arow = tid >> 1;
  const int acol = (tid & 1) * 8;
  const int wrow = tid >> 4;
  const int wcol = (tid & 15) * 8;
  const bool arow_ok = (m0 + arow) < M;

  float acc[8][8] = {};

  for (int k0 = 0; k0 < K; k0 += 16) {
    float4 av0 = make_float4(0.f,0.f,0.f,0.f), av1 = av0;
    if (arow_ok) {
      const float* ap = A + (size_t)(m0 + arow) * K + (k0 + acol);
      av0 = *(const float4*)(ap);
      av1 = *(const float4*)(ap + 4);
    }
    const float* wp = W + (size_t)(k0 + wrow) * N + (n0 + wcol);
    float4 wv0 = *(const float4*)(wp);
    float4 wv1 = *(const float4*)(wp + 4);
    __syncthreads();
    As[acol+0][arow] = av0.x; As[acol+1][arow] = av0.y;
    As[acol+2][arow] = av0.z; As[acol+3][arow] = av0.w;
    As[acol+4][arow] = av1.x; As[acol+5][arow] = av1.y;
    As[acol+6][arow] = av1.z; As[acol+7][arow] = av1.w;
    *(float4*)&Ws[wrow][wcol]   = wv0;
    *(float4*)&Ws[wrow][wcol+4] = wv1;
    __syncthreads();
    #pragma unroll
    for (int k = 0; k < 16; ++k) {
      float4 a0 = *(const float4*)&As[k][ty*4];
      float4 a1 = *(const float4*)&As[k][ty*4 + 64];
      float4 b0 = *(const float4*)&Ws[k][tx*4];
      float4 b1 = *(const float4*)&Ws[k][tx*4 + 64];
      float ar[8] = {a0.x,a0.y,a0.z,a0.w,a1.x,a1.y,a1.z,a1.w};
      float br[8] = {b0.x,b0.y,b0.z,b0.w,b1.x,b1.y,b1.z,b1.w};
      #pragma unroll
      for (int i = 0; i < 8; ++i)
        #pragma unroll
        for (int j = 0; j < 8; ++j)
          acc[i][j] = fmaf(ar[i], br[j], acc[i][j]);
    }
  }

  #pragma unroll
  for (int ih = 0; ih < 2; ++ih) {
    #pragma unroll
    for (int i = 0; i < 4; ++i) {
      const int m = m0 + ih*64 + ty*4 + i;
      if (m >= M) continue;
      #pragma unroll
      for (int jh = 0; jh < 2; ++jh) {
        const int n = n0 + jh*64 + tx*4;
        float4 bs = *(const float4*)&bias[n];
        float r0 = acc[ih*4+i][jh*4+0] + bs.x;
        float r1 = acc[ih*4+i][jh*4+1] + bs.y;
        float r2 = acc[ih*4+i][jh*4+2] + bs.z;
        float r3 = acc[ih*4+i][jh*4+3] + bs.w;
        if (MODE == MODE_GELU) { r0=gelu_f(r0); r1=gelu_f(r1); r2=gelu_f(r2); r3=gelu_f(r3); }
        float* p = C + (size_t)m * N + n;
        if (MODE == MODE_ADD) {
          float4 old = *(const float4*)p;
          r0 += old.x; r1 += old.y; r2 += old.z; r3 += old.w;
        }
        *(float4*)p = make_float4(r0,r1,r2,r3);
      }
    }
  }
}

// ---------------- weight transpose + split: W[K][N] fp32 -> Whi/Wlo [N][K] bf16 ----------------
__global__ __launch_bounds__(256) void wsplit_k(
    const float* __restrict__ W, unsigned short* __restrict__ Whi,
    unsigned short* __restrict__ Wlo, int K, int N)
{
  __shared__ float tile[64][65];
  const int k0 = blockIdx.y * 64, n0 = blockIdx.x * 64;
  const int r = threadIdx.x >> 4;        // 0..15
  const int c = (threadIdx.x & 15) * 4;  // 0..60
  #pragma unroll
  for (int i = 0; i < 64; i += 16) {
    float4 v = *(const float4*)&W[(size_t)(k0 + r + i) * N + n0 + c];
    tile[r+i][c+0] = v.x; tile[r+i][c+1] = v.y; tile[r+i][c+2] = v.z; tile[r+i][c+3] = v.w;
  }
  __syncthreads();
  #pragma unroll
  for (int i = 0; i < 64; i += 16) {
    const int n = n0 + r + i;
    float x0 = tile[c+0][r+i], x1 = tile[c+1][r+i], x2 = tile[c+2][r+i], x3 = tile[c+3][r+i];
    split_store4(&Whi[(size_t)n*K + k0 + c], &Wlo[(size_t)n*K + k0 + c], x0, x1, x2, x3);
  }
}

// ---------------- MFMA split-bf16 GEMM ----------------
// C[M][N] = op(A[M][K] @ Bt[N][K]^T + bias) with A,Bt as (hi,lo) bf16 planes.
// 128x128 tile, BK=32, 4 waves each computing 4x4 grid of 16x16x32 mfma tiles.
// 3 MFMA per logical product: hi*hi + hi*lo + lo*hi.
// LDS columns XOR-swizzled (slot = (kg + (row>>1)) & 3) so frag ds_read_b128s
// are 2-way (free) while staging stays global_load_lds-contiguous (swizzle is
// compensated in the per-lane global source address).
template<int MODE>
__global__ __launch_bounds__(256) void gemm_mfma_k(
    const unsigned short* __restrict__ Ahi, const unsigned short* __restrict__ Alo, int lda,
    const unsigned short* __restrict__ Bhi, const unsigned short* __restrict__ Blo, int ldb,
    const float* __restrict__ bias,
    float* __restrict__ Cf, unsigned short* __restrict__ Chi, unsigned short* __restrict__ Clo,
    int ldc, int M, int N, int K)
{
  __shared__ __align__(16) short sA[2][128*32];
  __shared__ __align__(16) short sB[2][128*32];
  const int tid = threadIdx.x;
  const int wid = tid >> 6;
  const int lane = tid & 63;
  const int m0 = blockIdx.y * 128;
  const int n0 = blockIdx.x * 128;
  const int wm = (wid & 1) * 64;
  const int wn = (wid >> 1) * 64;
  const int lm = lane & 15;
  const int kg = lane >> 4;

  // staging role: wave 0 -> A hi, 1 -> A lo, 2 -> B hi, 3 -> B lo
  const unsigned short* gsrc = (wid==0)?Ahi:(wid==1)?Alo:(wid==2)?Bhi:Blo;
  const int gld   = (wid < 2) ? lda : ldb;
  const int grow0 = (wid < 2) ? m0 : n0;
  short* sdst = (wid==0)?sA[0]:(wid==1)?sA[1]:(wid==2)?sB[0]:sB[1];
  const int srow = lane >> 2;                                   // row within 16-row chunk
  const int gcol = (((lane & 3) - ((lane >> 3) & 3)) & 3) * 8;  // swizzle-compensated k offset

  // precomputed swizzled frag offsets
  int aoff[4], boff[4];
  #pragma unroll
  for (int i = 0; i < 4; ++i) {
    const int am = wm + i*16 + lm;
    aoff[i] = am*32 + (((kg + (am >> 1)) & 3) * 8);
    const int bn = wn + i*16 + lm;
    boff[i] = bn*32 + (((kg + (bn >> 1)) & 3) * 8);
  }

  f32x4_t acc[4][4];
  const f32x4_t zz4 = {0.f, 0.f, 0.f, 0.f};
  #pragma unroll
  for (int i = 0; i < 4; ++i)
    #pragma unroll
    for (int j = 0; j < 4; ++j) acc[i][j] = zz4;

  for (int k0 = 0; k0 < K; k0 += 32) {
    __syncthreads();
    #pragma unroll
    for (int rg = 0; rg < 8; ++rg) {
      const unsigned short* g = gsrc + (size_t)(grow0 + rg*16 + srow) * gld + (k0 + gcol);
      __builtin_amdgcn_global_load_lds((gconst_t*)g, (ldsvoid_t*)(sdst + rg*16*32), 16, 0, 0);
    }
    __syncthreads();
    bf16x8 ah[4], al[4], bh[4], bl[4];
    #pragma unroll
    for (int i = 0; i < 4; ++i) {
      ah[i] = *(const bf16x8*)&sA[0][aoff[i]];
      al[i] = *(const bf16x8*)&sA[1][aoff[i]];
      bh[i] = *(const bf16x8*)&sB[0][boff[i]];
      bl[i] = *(const bf16x8*)&sB[1][boff[i]];
    }
    #pragma unroll
    for (int i = 0; i < 4; ++i)
      #pragma unroll
      for (int j = 0; j < 4; ++j) {
        acc[i][j] = __builtin_amdgcn_mfma_f32_16x16x32_bf16(ah[i], bh[j], acc[i][j], 0, 0, 0);
        acc[i][j] = __builtin_amdgcn_mfma_f32_16x16x32_bf16(ah[i], bl[j], acc[i][j], 0, 0, 0);
        acc[i][j] = __builtin_amdgcn_mfma_f32_16x16x32_bf16(al[i], bh[j], acc[i][j], 0, 0, 0);
      }
  }

  // epilogue: C/D layout col = lane&15, row = (lane>>4)*4 + reg   [m89-verified]
  const int er = kg * 4;
  const int ec = lm;
  #pragma unroll
  for (int i = 0; i < 4; ++i) {
    #pragma unroll
    for (int j = 0; j < 4; ++j) {
      const int n = n0 + wn + j*16 + ec;
      const float bs = bias[n];
      #pragma unroll
      for (int r = 0; r < 4; ++r) {
        const int m = m0 + wm + i*16 + er + r;
        const size_t idx = (size_t)m * ldc + n;
        float v = acc[i][j][r] + bs;
        if (MODE == GM_STORE) {
          Cf[idx] = v;
        } else if (MODE == GM_ADD) {
          Cf[idx] += v;
        } else {  // GM_GELU_SPLIT
          const float gl = gelu_f(v);
          const unsigned short hb = f2bf(gl);
          Chi[idx] = hb;
          Clo[idx] = f2bf(gl - bf2f(hb));
        }
      }
    }
  }
}

// ---------------- LayerNorm ----------------
template<bool SPLIT>
__global__ __launch_bounds__(256) void ln_k(
    const float* __restrict__ X, size_t xstride, float* __restrict__ Yf,
    unsigned short* __restrict__ Yh, unsigned short* __restrict__ Yl,
    const float* __restrict__ g, const float* __restrict__ b)
{
  const int row = blockIdx.x;
  const int t = threadIdx.x;
  const float* x = X + (size_t)row * xstride;
  __shared__ float red[4];
  float4 v = ((const float4*)x)[t];
  float s = v.x + v.y + v.z + v.w;
  #pragma unroll
  for (int o = 32; o > 0; o >>= 1) s += __shfl_down(s, o);
  const int wave = t >> 6, lane = t & 63;
  if (lane == 0) red[wave] = s;
  __syncthreads();
  const float mean = (red[0]+red[1]+red[2]+red[3]) * (1.0f/1024.0f);
  float4 d;
  d.x = v.x - mean; d.y = v.y - mean; d.z = v.z - mean; d.w = v.w - mean;
  float ss = d.x*d.x + d.y*d.y + d.z*d.z + d.w*d.w;
  __syncthreads();
  #pragma unroll
  for (int o = 32; o > 0; o >>= 1) ss += __shfl_down(ss, o);
  if (lane == 0) red[wave] = ss;
  __syncthreads();
  const float var = (red[0]+red[1]+red[2]+red[3]) * (1.0f/1024.0f);
  const float inv = rsqrtf(var + 1e-5f);
  float4 gg = ((const float4*)g)[t];
  float4 bb = ((const float4*)b)[t];
  float o0 = d.x * inv * gg.x + bb.x;
  float o1 = d.y * inv * gg.y + bb.y;
  float o2 = d.z * inv * gg.z + bb.z;
  float o3 = d.w * inv * gg.w + bb.w;
  if (SPLIT) {
    split_store4(Yh + (size_t)row*DD + 4*t, Yl + (size_t)row*DD + 4*t, o0, o1, o2, o3);
  } else {
    ((float4*)(Yf + (size_t)row*DD))[t] = make_float4(o0,o1,o2,o3);
  }
}

// ---------------- h += pos ----------------
__global__ __launch_bounds__(256) void addpos_k(float* __restrict__ H, const float* __restrict__ pos)
{
  const size_t i = (size_t)blockIdx.x * 256 + threadIdx.x;
  float4 v = ((const float4*)H)[i];
  const size_t row = i >> 8;
  const int tt = (int)(row & (TT-1));
  float4 p = ((const float4*)pos)[(size_t)tt * 256 + (i & 255)];
  v.x += p.x; v.y += p.y; v.z += p.z; v.w += p.w;
  ((float4*)H)[i] = v;
}

// ---------------- causal attention, flash-style ----------------
template<bool SPLIT>
__global__ __launch_bounds__(256) void attn_k(
    const float* __restrict__ QKV, float* __restrict__ Of,
    unsigned short* __restrict__ Oh, unsigned short* __restrict__ Ol)
{
  const int qt = blockIdx.x;
  const int bh = blockIdx.y;
  const int b  = bh >> 4;
  const int hh = bh & 15;
  const int tid = threadIdx.x;
  const int r = tid >> 2;
  const int g = tid & 3;
  __shared__ float Qs[64][68];
  __shared__ float Ks[64][68];
  __shared__ float Vs[64][68];

  {
    const int i = tid >> 2;
    const int c = (tid & 3) * 16;
    const float* qp = QKV + (size_t)(b*TT + qt*64 + i) * 3072 + hh*64 + c;
    #pragma unroll
    for (int j = 0; j < 16; j += 4)
      *(float4*)&Qs[i][c+j] = *(const float4*)(qp + j);
  }

  float o[64];
  #pragma unroll
  for (int d = 0; d < 64; ++d) o[d] = 0.0f;
  float mrow = -1e30f, lrow = 0.0f;
  const int q_global = qt*64 + r;
  const float scale = 0.125f;

  for (int kt = 0; kt <= qt; ++kt) {
    __syncthreads();
    {
      const int i = tid >> 2;
      const int c = (tid & 3) * 16;
      const float* kp = QKV + (size_t)(b*TT + kt*64 + i) * 3072 + 1024 + hh*64 + c;
      const float* vp = kp + 1024;
      #pragma unroll
      for (int j = 0; j < 16; j += 4) {
        *(float4*)&Ks[i][c+j] = *(const float4*)(kp + j);
        *(float4*)&Vs[i][c+j] = *(const float4*)(vp + j);
      }
    }
    __syncthreads();

    float s[16];
    #pragma unroll
    for (int j = 0; j < 16; ++j) s[j] = 0.0f;
    #pragma unroll
    for (int d0 = 0; d0 < 64; d0 += 4) {
      float4 q4 = *(const float4*)&Qs[r][d0];
      #pragma unroll
      for (int j = 0; j < 16; ++j) {
        float4 k4 = *(const float4*)&Ks[g + 4*j][d0];
        s[j] = fmaf(q4.x,k4.x, fmaf(q4.y,k4.y, fmaf(q4.z,k4.z, fmaf(q4.w,k4.w, s[j]))));
      }
    }
    float tmax = -1e30f;
    #pragma unroll
    for (int j = 0; j < 16; ++j) {
      const int kgl = kt*64 + g + 4*j;
      s[j] = (kgl <= q_global) ? s[j]*scale : -1e30f;
      tmax = fmaxf(tmax, s[j]);
    }
    tmax = fmaxf(tmax, __shfl_xor(tmax, 1));
    tmax = fmaxf(tmax, __shfl_xor(tmax, 2));
    const float mnew = fmaxf(mrow, tmax);
    const float alpha = expf(mrow - mnew);
    float p[16];
    float psum = 0.0f;
    #pragma unroll
    for (int j = 0; j < 16; ++j) { p[j] = expf(s[j] - mnew); psum += p[j]; }
    psum += __shfl_xor(psum, 1);
    psum += __shfl_xor(psum, 2);
    lrow = lrow * alpha + psum;
    #pragma unroll
    for (int d = 0; d < 64; ++d) o[d] *= alpha;
    #pragma unroll
    for (int j = 0; j < 16; ++j) {
      const float pj = p[j];
      #pragma unroll
      for (int d0 = 0; d0 < 64; d0 += 4) {
        float4 v4 = *(const float4*)&Vs[g + 4*j][d0];
        o[d0+0] = fmaf(pj, v4.x, o[d0+0]);
        o[d0+1] = fmaf(pj, v4.y, o[d0+1]);
        o[d0+2] = fmaf(pj, v4.z, o[d0+2]);
        o[d0+3] = fmaf(pj, v4.w, o[d0+3]);
      }
    }
    mrow = mnew;
  }

  #pragma unroll
  for (int d = 0; d < 64; ++d) {
    o[d] += __shfl_xor(o[d], 1);
    o[d] += __shfl_xor(o[d], 2);
  }
  const float invl = 1.0f / lrow;
  const size_t base = (size_t)(b*TT + q_global) * DD + hh*64 + g*16;
  if (SPLIT) {
    #pragma unroll
    for (int j = 0; j < 16; j += 4)
      split_store4(Oh + base + j, Ol + base + j,
                   o[g*16+j+0]*invl, o[g*16+j+1]*invl, o[g*16+j+2]*invl, o[g*16+j+3]*invl);
  } else {
    float* dst = Of + base;
    #pragma unroll
    for (int j = 0; j < 16; j += 4) {
      float4 w;
      w.x = o[g*16+j+0]*invl; w.y = o[g*16+j+1]*invl;
      w.z = o[g*16+j+2]*invl; w.w = o[g*16+j+3]*invl;
      *(float4*)(dst + j) = w;
    }
  }
}

// ---------------- residual VQ ----------------
__global__ __launch_bounds__(256) void rvq_k(
    const float* __restrict__ Z, const float* __restrict__ CB,
    const float* __restrict__ LS, float* __restrict__ OUT)
{
  const int b = blockIdx.x;
  const int t = threadIdx.x;
  __shared__ float rr[256];
  __shared__ float sred[256];
  __shared__ int   sidx[256];
  rr[t] = Z[b*OO + t];
  float acc = 0.0f;
  __syncthreads();
  for (int i = 0; i < QQ; ++i) {
    {
      const float x = rr[t];
      sred[t] = x * x;
    }
    __syncthreads();
    for (int s = 128; s > 0; s >>= 1) {
      if (t < s) sred[t] += sred[t + s];
      __syncthreads();
    }
    const float rsq = sred[0];
    __syncthreads();

    const float* cb = CB + (size_t)i * KK * OO;
    float best = 3.0e38f;
    int bj = 0;
    for (int j0 = 0; j0 < KK; j0 += 256) {
      const int j = j0 + t;
      const float* e = cb + (size_t)j * OO;
      float esq = 0.0f, dot = 0.0f;
      #pragma unroll 4
      for (int o = 0; o < OO; o += 4) {
        float4 e4 = *(const float4*)(e + o);
        esq = fmaf(e4.x,e4.x, fmaf(e4.y,e4.y, fmaf(e4.z,e4.z, fmaf(e4.w,e4.w, esq))));
        dot = fmaf(rr[o],e4.x, fmaf(rr[o+1],e4.y, fmaf(rr[o+2],e4.z, fmaf(rr[o+3],e4.w, dot))));
      }
      const float d = rsq + esq - 2.0f*dot;
      if (d < best) { best = d; bj = j; }
    }
    sred[t] = best; sidx[t] = bj;
    __syncthreads();
    for (int s = 128; s > 0; s >>= 1) {
      if (t < s) {
        const float d2 = sred[t+s]; const int i2 = sidx[t+s];
        if (d2 < sred[t] || (d2 == sred[t] && i2 < sidx[t])) { sred[t] = d2; sidx[t] = i2; }
      }
      __syncthreads();
    }
    const int bestj = sidx[0];
    __syncthreads();
    const float zq  = cb[(size_t)bestj * OO + t];
    const float ls  = LS[i];
    const float sig = 1.0f / (1.0f + expf(-ls));
    acc = fmaf(sig, zq, acc);
    rr[t] -= zq;
    __syncthreads();
  }
  OUT[b*OO + t] = acc;
}

// ---------------- host launch ----------------
extern "C" void kernel_launch(void* const* d_in, const int* in_sizes, int n_in,
                              void* d_out, int out_size, void* d_ws, size_t ws_size,
                              hipStream_t stream) {
  const float* x       = (const float*)d_in[0];
  const float* w_in    = (const float*)d_in[1];
  const float* b_in    = (const float*)d_in[2];
  const float* pos     = (const float*)d_in[3];
  const float* ln1_g   = (const float*)d_in[4];
  const float* ln1_b   = (const float*)d_in[5];
  const float* qkv_w   = (const float*)d_in[6];
  const float* qkv_b   = (const float*)d_in[7];
  const float* proj_w  = (const float*)d_in[8];
  const float* proj_b  = (const float*)d_in[9];
  const float* ln2_g   = (const float*)d_in[10];
  const float* ln2_b   = (const float*)d_in[11];
  const float* ff1_w   = (const float*)d_in[12];
  const float* ff1_b   = (const float*)d_in[13];
  const float* ff2_w   = (const float*)d_in[14];
  const float* ff2_b   = (const float*)d_in[15];
  const float* lnf_g   = (const float*)d_in[16];
  const float* lnf_b   = (const float*)d_in[17];
  const float* out1_w  = (const float*)d_in[18];
  const float* out1_b  = (const float*)d_in[19];
  const float* out2_w  = (const float*)d_in[20];
  const float* out2_b  = (const float*)d_in[21];
  const float* codebooks    = (const float*)d_in[22];
  const float* layer_scales = (const float*)d_in[23];

  float* ws  = (float*)d_ws;
  const size_t avail_f = ws_size / sizeof(float);
  const dim3 blk(256);

  // ---- layout (in float units) ----
  const size_t f_h   = (size_t)NTOK * DD;                 // h fp32
  const size_t f_ap  = (size_t)NTOK * DD;                 // act planes (2 x bf16 = 4B/elem)
  const size_t f_wt  = (size_t)FFD * DD;                  // wt planes (2 x bf16 of max N*K)
  const size_t f_sm  = (size_t)BB*DD + (size_t)BB*DD + (size_t)BB*OO + 16;

  float* h = ws;
  // MFMA path layout
  size_t off = f_h;
  unsigned short* ahi = (unsigned short*)(ws + off);       // NTOK*DD bf16
  unsigned short* alo = ahi + (size_t)NTOK * DD;           // NTOK*DD bf16
  off += f_ap;
  unsigned short* wth = (unsigned short*)(ws + off);       // plane 0
  unsigned short* wtl = wth + (size_t)FFD * DD;            // plane 1
  off += f_wt;
  float* hl = ws + off;           off += (size_t)BB * DD;
  float* z1 = ws + off;           off += (size_t)BB * DD;
  float* zz = ws + off;           off += (size_t)BB * OO + 16;
  float* big = ws + off;
  const size_t big_f_mfma = (avail_f > off) ? (avail_f - off) : 0;

  const size_t qkv_row_f = (size_t)TT * 3 * DD;            // per-batch qkv fp32 floats
  const bool use_mfma = big_f_mfma >= qkv_row_f;           // need >= 1 batch of qkv

  if (use_mfma) {
    int nbc = (int)(big_f_mfma / qkv_row_f);
    if (nbc < 1) nbc = 1;
    if (nbc > BB) nbc = BB;
    int mc = (int)((big_f_mfma / FFD) / 128) * 128;        // ff chunk rows (planes: FFD floats/row)
    if (mc < 128) mc = 128;
    if (mc > NTOK) mc = NTOK;
    unsigned short* bighi = (unsigned short*)big;
    unsigned short* biglo = bighi + (size_t)mc * FFD;

    gemm_k<MODE_STORE><<<dim3(DD/128, NTOK/128), blk, 0, stream>>>(x, w_in, b_in, h, NTOK, DD, CC);
    addpos_k<<<NTOK, blk, 0, stream>>>(h, pos);

    for (int l = 0; l < LL; ++l) {
      ln_k<true><<<NTOK, blk, 0, stream>>>(h, DD, nullptr, ahi, alo, ln1_g + l*DD, ln1_b + l*DD);
      // qkv weights -> wt planes
      wsplit_k<<<dim3(3*DD/64, DD/64), blk, 0, stream>>>(qkv_w + (size_t)l*DD*3*DD, wth, wtl, DD, 3*DD);
      for (int b0 = 0; b0 < BB; b0 += nbc) {
        const int nb = (b0 + nbc <= BB) ? nbc : (BB - b0);
        const int Mq = nb * TT;
        gemm_mfma_k<GM_STORE><<<dim3(3*DD/128, Mq/128), blk, 0, stream>>>(
            ahi + (size_t)b0*TT*DD, alo + (size_t)b0*TT*DD, DD,
            wth, wtl, DD, qkv_b + (size_t)l*3*DD,
            big, nullptr, nullptr, 3*DD, Mq, 3*DD, DD);
        attn_k<true><<<dim3(TT/64, nb*HH_), blk, 0, stream>>>(
            big, nullptr, ahi + (size_t)b0*TT*DD, alo + (size_t)b0*TT*DD);
      }
      // proj
      wsplit_k<<<dim3(DD/64, DD/64), blk, 0, stream>>>(proj_w + (size_t)l*DD*DD, wth, wtl, DD, DD);
      gemm_mfma_k<GM_ADD><<<dim3(DD/128, NTOK/128), blk, 0, stream>>>(
          ahi, alo, DD, wth, wtl, DD, proj_b + (size_t)l*DD,
          h, nullptr, nullptr, DD, NTOK, DD, DD);
      ln_k<true><<<NTOK, blk, 0, stream>>>(h, DD, nullptr, ahi, alo, ln2_g + l*DD, ln2_b + l*DD);
      // ff1 weights
      wsplit_k<<<dim3(FFD/64, DD/64), blk, 0, stream>>>(ff1_w + (size_t)l*DD*FFD, wth, wtl, DD, FFD);
      for (int r0 = 0; r0 < NTOK; r0 += mc) {
        const int mr = (r0 + mc <= NTOK) ? mc : (NTOK - r0);
        gemm_mfma_k<GM_GELU_SPLIT><<<dim3(FFD/128, mr/128), blk, 0, stream>>>(
            ahi + (size_t)r0*DD, alo + (size_t)r0*DD, DD,
            wth, wtl, DD, ff1_b + (size_t)l*FFD,
            nullptr, bighi, biglo, FFD, mr, FFD, DD);
        // ff2 weights (overwrites wt; re-split every chunk for stream ordering)
        wsplit_k<<<dim3(DD/64, FFD/64), blk, 0, stream>>>(ff2_w + (size_t)l*FFD*DD, wth, wtl, FFD, DD);
        gemm_mfma_k<GM_ADD><<<dim3(DD/128, mr/128), blk, 0, stream>>>(
            bighi, biglo, FFD, wth, wtl, FFD, ff2_b + (size_t)l*DD,
            h + (size_t)r0*DD, nullptr, nullptr, DD, mr, DD, FFD);
        if (r0 + mc < NTOK)  // next chunk needs ff1 weights again
          wsplit_k<<<dim3(FFD/64, DD/64), blk, 0, stream>>>(ff1_w + (size_t)l*DD*FFD, wth, wtl, DD, FFD);
      }
    }

    ln_k<false><<<BB, blk, 0, stream>>>(h + (size_t)(TT-1)*DD, (size_t)TT*DD, hl, nullptr, nullptr, lnf_g, lnf_b);
    gemm_k<MODE_GELU><<<dim3(DD/128, 1), blk, 0, stream>>>(hl, out1_w, out1_b, z1, BB, DD, DD);
    gemm_k<MODE_STORE><<<dim3(OO/128, 1), blk, 0, stream>>>(z1, out2_w, out2_b, zz, BB, OO, DD);
    rvq_k<<<BB, blk, 0, stream>>>(zz, codebooks, layer_scales, (float*)d_out);
    return;
  }

  // ---------------- fallback: pure fp32 path (round-2, verified) ----------------
  {
    float* a   = ws + f_h;
    float* hl2 = a + f_ap;
    float* z12 = hl2 + (size_t)BB * DD;
    float* zz2 = z12 + (size_t)BB * DD;
    float* big2 = zz2 + (size_t)BB * OO;
    const size_t base_f = (size_t)(big2 - ws);
    const size_t big_f = (avail_f > base_f) ? (avail_f - base_f) : 0;
    int nbc = (int)(big_f / qkv_row_f);
    if (nbc < 1) nbc = 1;
    if (nbc > BB) nbc = BB;
    int mc = (int)((big_f / FFD) / 128) * 128;
    if (mc < 128) mc = 128;
    if (mc > NTOK) mc = NTOK;

    gemm_k<MODE_STORE><<<dim3(DD/128, NTOK/128), blk, 0, stream>>>(x, w_in, b_in, h, NTOK, DD, CC);
    addpos_k<<<NTOK, blk, 0, stream>>>(h, pos);
    for (int l = 0; l < LL; ++l) {
      ln_k<false><<<NTOK, blk, 0, stream>>>(h, DD, a, nullptr, nullptr, ln1_g + l*DD, ln1_b + l*DD);
      for (int b0 = 0; b0 < BB; b0 += nbc) {
        const int nb = (b0 + nbc <= BB) ? nbc : (BB - b0);
        const int Mq = nb * TT;
        gemm_k<MODE_STORE><<<dim3((3*DD)/128, Mq/128), blk, 0, stream>>>(
            a + (size_t)b0*TT*DD, qkv_w + (size_t)l*DD*3*DD, qkv_b + (size_t)l*3*DD,
            big2, Mq, 3*DD, DD);
        attn_k<false><<<dim3(TT/64, nb*HH_), blk, 0, stream>>>(big2, a + (size_t)b0*TT*DD, nullptr, nullptr);
      }
      gemm_k<MODE_ADD><<<dim3(DD/128, NTOK/128), blk, 0, stream>>>(
          a, proj_w + (size_t)l*DD*DD, proj_b + (size_t)l*DD, h, NTOK, DD, DD);
      ln_k<false><<<NTOK, blk, 0, stream>>>(h, DD, a, nullptr, nullptr, ln2_g + l*DD, ln2_b + l*DD);
      for (int r0 = 0; r0 < NTOK; r0 += mc) {
        const int mr = (r0 + mc <= NTOK) ? mc : (NTOK - r0);
        gemm_k<MODE_GELU><<<dim3(FFD/128, mr/128), blk, 0, stream>>>(
            a + (size_t)r0*DD, ff1_w + (size_t)l*DD*FFD, ff1_b + (size_t)l*FFD,
            big2, mr, FFD, DD);
        gemm_k<MODE_ADD><<<dim3(DD/128, mr/128), blk, 0, stream>>>(
            big2, ff2_w + (size_t)l*FFD*DD, ff2_b + (size_t)l*DD, h + (size_t)r0*DD, mr, DD, FFD);
      }
    }
    ln_k<false><<<BB, blk, 0, stream>>>(h + (size_t)(TT-1)*DD, (size_t)TT*DD, hl2, nullptr, nullptr, lnf_g, lnf_b);
    gemm_k<MODE_GELU><<<dim3(DD/128, 1), blk, 0, stream>>>(hl2, out1_w, out1_b, z12, BB, DD, DD);
    gemm_k<MODE_STORE><<<dim3(OO/128, 1), blk, 0, stream>>>(z12, out2_w, out2_b, zz2, BB, OO, DD);
    rvq_k<<<BB, blk, 0, stream>>>(zz2, codebooks, layer_scales, (float*)d_out);
  }
}

// Round 4
// 13421.448 us; speedup vs baseline: 3.0795x; 1.3948x over previous
//
#include <hip/hip_runtime.h>
#include <math.h>

// Problem dims
#define BB 32
#define TT 512
#define CC 256
#define DD 1024
#define HH_ 16
#define LL 6
#define FFD 4096
#define OO 256
#define QQ 8
#define KK 1024
#define NTOK (BB*TT)   // 16384

enum GemmMode { MODE_STORE=0, MODE_GELU=1, MODE_ADD=2 };
enum { GM_STORE=0, GM_GELU_SPLIT=1, GM_ADD=2 };

typedef short bf16x8 __attribute__((ext_vector_type(8)));
typedef float f32x4_t __attribute__((ext_vector_type(4)));
typedef const __attribute__((address_space(1))) void gconst_t;
typedef __attribute__((address_space(3))) void ldsvoid_t;

#define MFMA16(a,b,c) __builtin_amdgcn_mfma_f32_16x16x32_bf16(a,b,c,0,0,0)

__device__ __forceinline__ float gelu_f(float x){
  return 0.5f * x * (1.0f + erff(x * 0.70710678118654752f));
}

// bf16 bit helpers (RNE)
__device__ __forceinline__ unsigned short f2bf(float x){
  unsigned int u = __float_as_uint(x);
  unsigned int r = (u + 0x7fffu + ((u >> 16) & 1u)) >> 16;
  return (unsigned short)r;
}
__device__ __forceinline__ float bf2f(unsigned short b){
  return __uint_as_float(((unsigned int)b) << 16);
}
__device__ __forceinline__ void split_store4(unsigned short* ph, unsigned short* pl,
                                             float a, float b, float c, float d){
  union { unsigned short s[4]; uint2 u; } th, tl;
  th.s[0]=f2bf(a); tl.s[0]=f2bf(a - bf2f(th.s[0]));
  th.s[1]=f2bf(b); tl.s[1]=f2bf(b - bf2f(th.s[1]));
  th.s[2]=f2bf(c); tl.s[2]=f2bf(c - bf2f(th.s[2]));
  th.s[3]=f2bf(d); tl.s[3]=f2bf(d - bf2f(th.s[3]));
  *(uint2*)ph = th.u; *(uint2*)pl = tl.u;
}
// 16 floats -> 2x bf16x8 per plane (16B-aligned LDS writes)
__device__ __forceinline__ void store_split16(short* ph, short* pl, const float* f){
  union { unsigned short s[8]; bf16x8 v; } h, l;
  #pragma unroll
  for (int i = 0; i < 8; ++i) { h.s[i]=f2bf(f[i]); l.s[i]=f2bf(f[i]-bf2f(h.s[i])); }
  *(bf16x8*)ph = h.v; *(bf16x8*)pl = l.v;
  #pragma unroll
  for (int i = 0; i < 8; ++i) { h.s[i]=f2bf(f[8+i]); l.s[i]=f2bf(f[8+i]-bf2f(h.s[i])); }
  *(bf16x8*)(ph+8) = h.v; *(bf16x8*)(pl+8) = l.v;
}

// ---------------- fp32 GEMM (in-proj, head, fallback) ----------------
template<int MODE>
__global__ __launch_bounds__(256) void gemm_k(
    const float* __restrict__ A, const float* __restrict__ W,
    const float* __restrict__ bias, float* __restrict__ C,
    int M, int N, int K)
{
  __shared__ float As[16][132];
  __shared__ float Ws[16][132];
  const int tid = threadIdx.x;
  const int tx = tid & 15;
  const int ty = tid >> 4;
  const int m0 = blockIdx.y * 128;
  const int n0 = blockIdx.x * 128;
  const int arow = tid >> 1;
  const int acol = (tid & 1) * 8;
  const int wrow = tid >> 4;
  const int wcol = (tid & 15) * 8;
  const bool arow_ok = (m0 + arow) < M;

  float acc[8][8] = {};

  for (int k0 = 0; k0 < K; k0 += 16) {
    float4 av0 = make_float4(0.f,0.f,0.f,0.f), av1 = av0;
    if (arow_ok) {
      const float* ap = A + (size_t)(m0 + arow) * K + (k0 + acol);
      av0 = *(const float4*)(ap);
      av1 = *(const float4*)(ap + 4);
    }
    const float* wp = W + (size_t)(k0 + wrow) * N + (n0 + wcol);
    float4 wv0 = *(const float4*)(wp);
    float4 wv1 = *(const float4*)(wp + 4);
    __syncthreads();
    As[acol+0][arow] = av0.x; As[acol+1][arow] = av0.y;
    As[acol+2][arow] = av0.z; As[acol+3][arow] = av0.w;
    As[acol+4][arow] = av1.x; As[acol+5][arow] = av1.y;
    As[acol+6][arow] = av1.z; As[acol+7][arow] = av1.w;
    *(float4*)&Ws[wrow][wcol]   = wv0;
    *(float4*)&Ws[wrow][wcol+4] = wv1;
    __syncthreads();
    #pragma unroll
    for (int k = 0; k < 16; ++k) {
      float4 a0 = *(const float4*)&As[k][ty*4];
      float4 a1 = *(const float4*)&As[k][ty*4 + 64];
      float4 b0 = *(const float4*)&Ws[k][tx*4];
      float4 b1 = *(const float4*)&Ws[k][tx*4 + 64];
      float ar[8] = {a0.x,a0.y,a0.z,a0.w,a1.x,a1.y,a1.z,a1.w};
      float br[8] = {b0.x,b0.y,b0.z,b0.w,b1.x,b1.y,b1.z,b1.w};
      #pragma unroll
      for (int i = 0; i < 8; ++i)
        #pragma unroll
        for (int j = 0; j < 8; ++j)
          acc[i][j] = fmaf(ar[i], br[j], acc[i][j]);
    }
  }

  #pragma unroll
  for (int ih = 0; ih < 2; ++ih) {
    #pragma unroll
    for (int i = 0; i < 4; ++i) {
      const int m = m0 + ih*64 + ty*4 + i;
      if (m >= M) continue;
      #pragma unroll
      for (int jh = 0; jh < 2; ++jh) {
        const int n = n0 + jh*64 + tx*4;
        float4 bs = *(const float4*)&bias[n];
        float r0 = acc[ih*4+i][jh*4+0] + bs.x;
        float r1 = acc[ih*4+i][jh*4+1] + bs.y;
        float r2 = acc[ih*4+i][jh*4+2] + bs.z;
        float r3 = acc[ih*4+i][jh*4+3] + bs.w;
        if (MODE == MODE_GELU) { r0=gelu_f(r0); r1=gelu_f(r1); r2=gelu_f(r2); r3=gelu_f(r3); }
        float* p = C + (size_t)m * N + n;
        if (MODE == MODE_ADD) {
          float4 old = *(const float4*)p;
          r0 += old.x; r1 += old.y; r2 += old.z; r3 += old.w;
        }
        *(float4*)p = make_float4(r0,r1,r2,r3);
      }
    }
  }
}

// ---------------- weight transpose + split: W[K][N] fp32 -> Whi/Wlo [N][K] bf16 ----------------
__global__ __launch_bounds__(256) void wsplit_k(
    const float* __restrict__ W, unsigned short* __restrict__ Whi,
    unsigned short* __restrict__ Wlo, int K, int N)
{
  __shared__ float tile[64][65];
  const int k0 = blockIdx.y * 64, n0 = blockIdx.x * 64;
  const int r = threadIdx.x >> 4;
  const int c = (threadIdx.x & 15) * 4;
  #pragma unroll
  for (int i = 0; i < 64; i += 16) {
    float4 v = *(const float4*)&W[(size_t)(k0 + r + i) * N + n0 + c];
    tile[r+i][c+0] = v.x; tile[r+i][c+1] = v.y; tile[r+i][c+2] = v.z; tile[r+i][c+3] = v.w;
  }
  __syncthreads();
  #pragma unroll
  for (int i = 0; i < 64; i += 16) {
    const int n = n0 + r + i;
    float x0 = tile[c+0][r+i], x1 = tile[c+1][r+i], x2 = tile[c+2][r+i], x3 = tile[c+3][r+i];
    split_store4(&Whi[(size_t)n*K + k0 + c], &Wlo[(size_t)n*K + k0 + c], x0, x1, x2, x3);
  }
}

// ---------------- MFMA split-bf16 GEMM (unchanged from round 3, verified) ----------------
template<int MODE>
__global__ __launch_bounds__(256) void gemm_mfma_k(
    const unsigned short* __restrict__ Ahi, const unsigned short* __restrict__ Alo, int lda,
    const unsigned short* __restrict__ Bhi, const unsigned short* __restrict__ Blo, int ldb,
    const float* __restrict__ bias,
    float* __restrict__ Cf, unsigned short* __restrict__ Chi, unsigned short* __restrict__ Clo,
    int ldc, int M, int N, int K)
{
  __shared__ __align__(16) short sA[2][128*32];
  __shared__ __align__(16) short sB[2][128*32];
  const int tid = threadIdx.x;
  const int wid = tid >> 6;
  const int lane = tid & 63;
  const int m0 = blockIdx.y * 128;
  const int n0 = blockIdx.x * 128;
  const int wm = (wid & 1) * 64;
  const int wn = (wid >> 1) * 64;
  const int lm = lane & 15;
  const int kg = lane >> 4;

  const unsigned short* gsrc = (wid==0)?Ahi:(wid==1)?Alo:(wid==2)?Bhi:Blo;
  const int gld   = (wid < 2) ? lda : ldb;
  const int grow0 = (wid < 2) ? m0 : n0;
  short* sdst = (wid==0)?sA[0]:(wid==1)?sA[1]:(wid==2)?sB[0]:sB[1];
  const int srow = lane >> 2;
  const int gcol = (((lane & 3) - ((lane >> 3) & 3)) & 3) * 8;

  int aoff[4], boff[4];
  #pragma unroll
  for (int i = 0; i < 4; ++i) {
    const int am = wm + i*16 + lm;
    aoff[i] = am*32 + (((kg + (am >> 1)) & 3) * 8);
    const int bn = wn + i*16 + lm;
    boff[i] = bn*32 + (((kg + (bn >> 1)) & 3) * 8);
  }

  f32x4_t acc[4][4];
  const f32x4_t zz4 = {0.f, 0.f, 0.f, 0.f};
  #pragma unroll
  for (int i = 0; i < 4; ++i)
    #pragma unroll
    for (int j = 0; j < 4; ++j) acc[i][j] = zz4;

  for (int k0 = 0; k0 < K; k0 += 32) {
    __syncthreads();
    #pragma unroll
    for (int rg = 0; rg < 8; ++rg) {
      const unsigned short* g = gsrc + (size_t)(grow0 + rg*16 + srow) * gld + (k0 + gcol);
      __builtin_amdgcn_global_load_lds((gconst_t*)g, (ldsvoid_t*)(sdst + rg*16*32), 16, 0, 0);
    }
    __syncthreads();
    bf16x8 ah[4], al[4], bh[4], bl[4];
    #pragma unroll
    for (int i = 0; i < 4; ++i) {
      ah[i] = *(const bf16x8*)&sA[0][aoff[i]];
      al[i] = *(const bf16x8*)&sA[1][aoff[i]];
      bh[i] = *(const bf16x8*)&sB[0][boff[i]];
      bl[i] = *(const bf16x8*)&sB[1][boff[i]];
    }
    #pragma unroll
    for (int i = 0; i < 4; ++i)
      #pragma unroll
      for (int j = 0; j < 4; ++j) {
        acc[i][j] = MFMA16(ah[i], bh[j], acc[i][j]);
        acc[i][j] = MFMA16(ah[i], bl[j], acc[i][j]);
        acc[i][j] = MFMA16(al[i], bh[j], acc[i][j]);
      }
  }

  const int er = kg * 4;
  const int ec = lm;
  #pragma unroll
  for (int i = 0; i < 4; ++i) {
    #pragma unroll
    for (int j = 0; j < 4; ++j) {
      const int n = n0 + wn + j*16 + ec;
      const float bs = bias[n];
      #pragma unroll
      for (int r = 0; r < 4; ++r) {
        const int m = m0 + wm + i*16 + er + r;
        const size_t idx = (size_t)m * ldc + n;
        float v = acc[i][j][r] + bs;
        if (MODE == GM_STORE) {
          Cf[idx] = v;
        } else if (MODE == GM_ADD) {
          Cf[idx] += v;
        } else {
          const float gl = gelu_f(v);
          const unsigned short hb = f2bf(gl);
          Chi[idx] = hb;
          Clo[idx] = f2bf(gl - bf2f(hb));
        }
      }
    }
  }
}

// ---------------- LayerNorm ----------------
template<bool SPLIT>
__global__ __launch_bounds__(256) void ln_k(
    const float* __restrict__ X, size_t xstride, float* __restrict__ Yf,
    unsigned short* __restrict__ Yh, unsigned short* __restrict__ Yl,
    const float* __restrict__ g, const float* __restrict__ b)
{
  const int row = blockIdx.x;
  const int t = threadIdx.x;
  const float* x = X + (size_t)row * xstride;
  __shared__ float red[4];
  float4 v = ((const float4*)x)[t];
  float s = v.x + v.y + v.z + v.w;
  #pragma unroll
  for (int o = 32; o > 0; o >>= 1) s += __shfl_down(s, o);
  const int wave = t >> 6, lane = t & 63;
  if (lane == 0) red[wave] = s;
  __syncthreads();
  const float mean = (red[0]+red[1]+red[2]+red[3]) * (1.0f/1024.0f);
  float4 d;
  d.x = v.x - mean; d.y = v.y - mean; d.z = v.z - mean; d.w = v.w - mean;
  float ss = d.x*d.x + d.y*d.y + d.z*d.z + d.w*d.w;
  __syncthreads();
  #pragma unroll
  for (int o = 32; o > 0; o >>= 1) ss += __shfl_down(ss, o);
  if (lane == 0) red[wave] = ss;
  __syncthreads();
  const float var = (red[0]+red[1]+red[2]+red[3]) * (1.0f/1024.0f);
  const float inv = rsqrtf(var + 1e-5f);
  float4 gg = ((const float4*)g)[t];
  float4 bb = ((const float4*)b)[t];
  float o0 = d.x * inv * gg.x + bb.x;
  float o1 = d.y * inv * gg.y + bb.y;
  float o2 = d.z * inv * gg.z + bb.z;
  float o3 = d.w * inv * gg.w + bb.w;
  if (SPLIT) {
    split_store4(Yh + (size_t)row*DD + 4*t, Yl + (size_t)row*DD + 4*t, o0, o1, o2, o3);
  } else {
    ((float4*)(Yf + (size_t)row*DD))[t] = make_float4(o0,o1,o2,o3);
  }
}

// ---------------- h += pos ----------------
__global__ __launch_bounds__(256) void addpos_k(float* __restrict__ H, const float* __restrict__ pos)
{
  const size_t i = (size_t)blockIdx.x * 256 + threadIdx.x;
  float4 v = ((const float4*)H)[i];
  const size_t row = i >> 8;
  const int tt = (int)(row & (TT-1));
  float4 p = ((const float4*)pos)[(size_t)tt * 256 + (i & 255)];
  v.x += p.x; v.y += p.y; v.z += p.z; v.w += p.w;
  ((float4*)H)[i] = v;
}

// ---------------- MFMA flash attention (split-bf16) ----------------
// One block per (b, hh, 64-row q-tile). 4 waves; wave w owns q-rows w*16..w*16+15.
// Q held in A-frags (regs). Per 64-key tile: stage K [key][d] and V^T [d][key]
// as hi/lo bf16 planes; S = QK^T (3-mfma split); online softmax on C-layout;
// P -> per-wave LDS region (A-layout round-trip, wave-private: lgkmcnt only);
// O += P V (3-mfma split). Rows padded to 72 bf16 = 144B (16B-aligned b128,
// 2-way banks = free).
#define AP 72
__global__ __launch_bounds__(256) void attn_mfma_k(
    const float* __restrict__ QKV,
    unsigned short* __restrict__ Oh, unsigned short* __restrict__ Ol)
{
  const int qt = blockIdx.x;
  const int bh = blockIdx.y;
  const int b  = bh >> 4;
  const int hh = bh & 15;
  const int tid  = threadIdx.x;
  const int w    = tid >> 6;
  const int lane = tid & 63;
  const int lm = lane & 15;
  const int kg = lane >> 4;

  __shared__ __align__(16) short sK[2][64*AP];
  __shared__ __align__(16) short sV[2][64*AP];   // V^T: [d][key]
  __shared__ __align__(16) short sP[2][64*AP];   // Q staging, then P

  const int srow = tid >> 2;          // 0..63 (token row)
  const int scol = (tid & 3) * 16;    // d-chunk base

  // ---- stage Q (wave w stages exactly its own rows) and load A-frags
  {
    const float* qp = QKV + (size_t)(b*TT + qt*64 + srow)*3072 + hh*64 + scol;
    float qf[16];
    #pragma unroll
    for (int i = 0; i < 4; ++i) {
      float4 q4 = ((const float4*)qp)[i];
      qf[4*i+0]=q4.x; qf[4*i+1]=q4.y; qf[4*i+2]=q4.z; qf[4*i+3]=q4.w;
    }
    store_split16(&sP[0][srow*AP+scol], &sP[1][srow*AP+scol], qf);
  }
  __syncthreads();
  bf16x8 qh[2], ql[2];
  #pragma unroll
  for (int st = 0; st < 2; ++st) {
    const int off = (w*16 + lm)*AP + st*32 + kg*8;
    qh[st] = *(const bf16x8*)&sP[0][off];
    ql[st] = *(const bf16x8*)&sP[1][off];
  }

  f32x4_t oacc[4];
  const f32x4_t z4 = {0.f,0.f,0.f,0.f};
  #pragma unroll
  for (int j = 0; j < 4; ++j) oacc[j] = z4;
  float m_r[4], l_r[4];
  #pragma unroll
  for (int r = 0; r < 4; ++r) { m_r[r] = -1e30f; l_r[r] = 0.0f; }
  const float scale = 0.125f;            // 1/sqrt(64)
  const int qrow_base = qt*64 + w*16 + kg*4;

  for (int kt = 0; kt <= qt; ++kt) {
    __syncthreads();   // prior tile's K/V reads done
    {
      const float* kp = QKV + (size_t)(b*TT + kt*64 + srow)*3072 + 1024 + hh*64 + scol;
      float kf[16], vf[16];
      #pragma unroll
      for (int i = 0; i < 4; ++i) {
        float4 k4 = ((const float4*)kp)[i];
        float4 v4 = ((const float4*)(kp + 1024))[i];
        kf[4*i+0]=k4.x; kf[4*i+1]=k4.y; kf[4*i+2]=k4.z; kf[4*i+3]=k4.w;
        vf[4*i+0]=v4.x; vf[4*i+1]=v4.y; vf[4*i+2]=v4.z; vf[4*i+3]=v4.w;
      }
      store_split16(&sK[0][srow*AP+scol], &sK[1][srow*AP+scol], kf);
      #pragma unroll
      for (int jj = 0; jj < 16; ++jj) {
        const unsigned short hb = f2bf(vf[jj]);
        sV[0][(scol+jj)*AP + srow] = (short)hb;
        sV[1][(scol+jj)*AP + srow] = (short)f2bf(vf[jj] - bf2f(hb));
      }
    }
    __syncthreads();

    // S = Q K^T  (C-frag: row q = kg*4+r, col key = j*16+lm)
    f32x4_t s[4];
    #pragma unroll
    for (int j = 0; j < 4; ++j) {
      f32x4_t acc = z4;
      #pragma unroll
      for (int st = 0; st < 2; ++st) {
        const int off = (j*16+lm)*AP + st*32 + kg*8;
        bf16x8 kbh = *(const bf16x8*)&sK[0][off];
        bf16x8 kbl = *(const bf16x8*)&sK[1][off];
        acc = MFMA16(qh[st], kbh, acc);
        acc = MFMA16(qh[st], kbl, acc);
        acc = MFMA16(ql[st], kbh, acc);
      }
      s[j] = acc;
    }
    // mask + scale + row max
    float tmax[4] = {-1e30f,-1e30f,-1e30f,-1e30f};
    #pragma unroll
    for (int j = 0; j < 4; ++j) {
      const int key = kt*64 + j*16 + lm;
      #pragma unroll
      for (int r = 0; r < 4; ++r) {
        const float v = (key <= qrow_base + r) ? s[j][r]*scale : -1e30f;
        s[j][r] = v;
        tmax[r] = fmaxf(tmax[r], v);
      }
    }
    #pragma unroll
    for (int r = 0; r < 4; ++r) {
      tmax[r] = fmaxf(tmax[r], __shfl_xor(tmax[r], 1));
      tmax[r] = fmaxf(tmax[r], __shfl_xor(tmax[r], 2));
      tmax[r] = fmaxf(tmax[r], __shfl_xor(tmax[r], 4));
      tmax[r] = fmaxf(tmax[r], __shfl_xor(tmax[r], 8));
    }
    float alpha[4];
    #pragma unroll
    for (int r = 0; r < 4; ++r) {
      const float mn = fmaxf(m_r[r], tmax[r]);
      alpha[r] = __expf(m_r[r] - mn);
      m_r[r] = mn;
    }
    float rsum[4] = {0.f,0.f,0.f,0.f};
    #pragma unroll
    for (int j = 0; j < 4; ++j)
      #pragma unroll
      for (int r = 0; r < 4; ++r) {
        const float p = __expf(s[j][r] - m_r[r]);
        s[j][r] = p;
        rsum[r] += p;
      }
    #pragma unroll
    for (int r = 0; r < 4; ++r) {
      rsum[r] += __shfl_xor(rsum[r], 1);
      rsum[r] += __shfl_xor(rsum[r], 2);
      rsum[r] += __shfl_xor(rsum[r], 4);
      rsum[r] += __shfl_xor(rsum[r], 8);
      l_r[r] = l_r[r]*alpha[r] + rsum[r];
    }
    // write P split to wave-private region (rows w*16 + kg*4 + r)
    #pragma unroll
    for (int j = 0; j < 4; ++j)
      #pragma unroll
      for (int r = 0; r < 4; ++r) {
        const int addr = (w*16 + kg*4 + r)*AP + j*16 + lm;
        const unsigned short hb = f2bf(s[j][r]);
        sP[0][addr] = (short)hb;
        sP[1][addr] = (short)f2bf(s[j][r] - bf2f(hb));
      }
    asm volatile("s_waitcnt lgkmcnt(0)" ::: "memory");  // wave-private: no barrier
    // rescale O
    #pragma unroll
    for (int j = 0; j < 4; ++j)
      #pragma unroll
      for (int r = 0; r < 4; ++r) oacc[j][r] *= alpha[r];
    // O += P V  (A = P rows w*16+lm, k = key; B = V^T rows d)
    bf16x8 ph_[2], pl_[2];
    #pragma unroll
    for (int st = 0; st < 2; ++st) {
      const int off = (w*16 + lm)*AP + st*32 + kg*8;
      ph_[st] = *(const bf16x8*)&sP[0][off];
      pl_[st] = *(const bf16x8*)&sP[1][off];
    }
    #pragma unroll
    for (int j = 0; j < 4; ++j) {
      #pragma unroll
      for (int st = 0; st < 2; ++st) {
        const int off = (j*16+lm)*AP + st*32 + kg*8;
        bf16x8 vbh = *(const bf16x8*)&sV[0][off];
        bf16x8 vbl = *(const bf16x8*)&sV[1][off];
        oacc[j] = MFMA16(ph_[st], vbh, oacc[j]);
        oacc[j] = MFMA16(ph_[st], vbl, oacc[j]);
        oacc[j] = MFMA16(pl_[st], vbh, oacc[j]);
      }
    }
  }

  // epilogue: split-store O (token rows = qrow_base + r, cols hh*64 + j*16 + lm)
  #pragma unroll
  for (int r = 0; r < 4; ++r) {
    const float invl = 1.0f / l_r[r];
    const size_t token = (size_t)(b*TT) + qrow_base + r;
    #pragma unroll
    for (int j = 0; j < 4; ++j) {
      const float v = oacc[j][r] * invl;
      const size_t addr = token*DD + hh*64 + j*16 + lm;
      const unsigned short hb = f2bf(v);
      Oh[addr] = hb;
      Ol[addr] = f2bf(v - bf2f(hb));
    }
  }
}

// ---------------- fp32 flash attention (fallback path only) ----------------
template<bool SPLIT>
__global__ __launch_bounds__(256) void attn_k(
    const float* __restrict__ QKV, float* __restrict__ Of,
    unsigned short* __restrict__ Oh, unsigned short* __restrict__ Ol)
{
  const int qt = blockIdx.x;
  const int bh = blockIdx.y;
  const int b  = bh >> 4;
  const int hh = bh & 15;
  const int tid = threadIdx.x;
  const int r = tid >> 2;
  const int g = tid & 3;
  __shared__ float Qs[64][68];
  __shared__ float Ks[64][68];
  __shared__ float Vs[64][68];

  {
    const int i = tid >> 2;
    const int c = (tid & 3) * 16;
    const float* qp = QKV + (size_t)(b*TT + qt*64 + i) * 3072 + hh*64 + c;
    #pragma unroll
    for (int j = 0; j < 16; j += 4)
      *(float4*)&Qs[i][c+j] = *(const float4*)(qp + j);
  }

  float o[64];
  #pragma unroll
  for (int d = 0; d < 64; ++d) o[d] = 0.0f;
  float mrow = -1e30f, lrow = 0.0f;
  const int q_global = qt*64 + r;
  const float scale = 0.125f;

  for (int kt = 0; kt <= qt; ++kt) {
    __syncthreads();
    {
      const int i = tid >> 2;
      const int c = (tid & 3) * 16;
      const float* kp = QKV + (size_t)(b*TT + kt*64 + i) * 3072 + 1024 + hh*64 + c;
      const float* vp = kp + 1024;
      #pragma unroll
      for (int j = 0; j < 16; j += 4) {
        *(float4*)&Ks[i][c+j] = *(const float4*)(kp + j);
        *(float4*)&Vs[i][c+j] = *(const float4*)(vp + j);
      }
    }
    __syncthreads();

    float s[16];
    #pragma unroll
    for (int j = 0; j < 16; ++j) s[j] = 0.0f;
    #pragma unroll
    for (int d0 = 0; d0 < 64; d0 += 4) {
      float4 q4 = *(const float4*)&Qs[r][d0];
      #pragma unroll
      for (int j = 0; j < 16; ++j) {
        float4 k4 = *(const float4*)&Ks[g + 4*j][d0];
        s[j] = fmaf(q4.x,k4.x, fmaf(q4.y,k4.y, fmaf(q4.z,k4.z, fmaf(q4.w,k4.w, s[j]))));
      }
    }
    float tmax = -1e30f;
    #pragma unroll
    for (int j = 0; j < 16; ++j) {
      const int kgl = kt*64 + g + 4*j;
      s[j] = (kgl <= q_global) ? s[j]*scale : -1e30f;
      tmax = fmaxf(tmax, s[j]);
    }
    tmax = fmaxf(tmax, __shfl_xor(tmax, 1));
    tmax = fmaxf(tmax, __shfl_xor(tmax, 2));
    const float mnew = fmaxf(mrow, tmax);
    const float alpha = expf(mrow - mnew);
    float p[16];
    float psum = 0.0f;
    #pragma unroll
    for (int j = 0; j < 16; ++j) { p[j] = expf(s[j] - mnew); psum += p[j]; }
    psum += __shfl_xor(psum, 1);
    psum += __shfl_xor(psum, 2);
    lrow = lrow * alpha + psum;
    #pragma unroll
    for (int d = 0; d < 64; ++d) o[d] *= alpha;
    #pragma unroll
    for (int j = 0; j < 16; ++j) {
      const float pj = p[j];
      #pragma unroll
      for (int d0 = 0; d0 < 64; d0 += 4) {
        float4 v4 = *(const float4*)&Vs[g + 4*j][d0];
        o[d0+0] = fmaf(pj, v4.x, o[d0+0]);
        o[d0+1] = fmaf(pj, v4.y, o[d0+1]);
        o[d0+2] = fmaf(pj, v4.z, o[d0+2]);
        o[d0+3] = fmaf(pj, v4.w, o[d0+3]);
      }
    }
    mrow = mnew;
  }

  #pragma unroll
  for (int d = 0; d < 64; ++d) {
    o[d] += __shfl_xor(o[d], 1);
    o[d] += __shfl_xor(o[d], 2);
  }
  const float invl = 1.0f / lrow;
  const size_t base = (size_t)(b*TT + q_global) * DD + hh*64 + g*16;
  if (SPLIT) {
    #pragma unroll
    for (int j = 0; j < 16; j += 4)
      split_store4(Oh + base + j, Ol + base + j,
                   o[g*16+j+0]*invl, o[g*16+j+1]*invl, o[g*16+j+2]*invl, o[g*16+j+3]*invl);
  } else {
    float* dst = Of + base;
    #pragma unroll
    for (int j = 0; j < 16; j += 4) {
      float4 w;
      w.x = o[g*16+j+0]*invl; w.y = o[g*16+j+1]*invl;
      w.z = o[g*16+j+2]*invl; w.w = o[g*16+j+3]*invl;
      *(float4*)(dst + j) = w;
    }
  }
}

// ---------------- residual VQ ----------------
__global__ __launch_bounds__(256) void rvq_k(
    const float* __restrict__ Z, const float* __restrict__ CB,
    const float* __restrict__ LS, float* __restrict__ OUT)
{
  const int b = blockIdx.x;
  const int t = threadIdx.x;
  __shared__ float rr[256];
  __shared__ float sred[256];
  __shared__ int   sidx[256];
  rr[t] = Z[b*OO + t];
  float acc = 0.0f;
  __syncthreads();
  for (int i = 0; i < QQ; ++i) {
    {
      const float x = rr[t];
      sred[t] = x * x;
    }
    __syncthreads();
    for (int s = 128; s > 0; s >>= 1) {
      if (t < s) sred[t] += sred[t + s];
      __syncthreads();
    }
    const float rsq = sred[0];
    __syncthreads();

    const float* cb = CB + (size_t)i * KK * OO;
    float best = 3.0e38f;
    int bj = 0;
    for (int j0 = 0; j0 < KK; j0 += 256) {
      const int j = j0 + t;
      const float* e = cb + (size_t)j * OO;
      float esq = 0.0f, dot = 0.0f;
      #pragma unroll 4
      for (int o = 0; o < OO; o += 4) {
        float4 e4 = *(const float4*)(e + o);
        esq = fmaf(e4.x,e4.x, fmaf(e4.y,e4.y, fmaf(e4.z,e4.z, fmaf(e4.w,e4.w, esq))));
        dot = fmaf(rr[o],e4.x, fmaf(rr[o+1],e4.y, fmaf(rr[o+2],e4.z, fmaf(rr[o+3],e4.w, dot))));
      }
      const float d = rsq + esq - 2.0f*dot;
      if (d < best) { best = d; bj = j; }
    }
    sred[t] = best; sidx[t] = bj;
    __syncthreads();
    for (int s = 128; s > 0; s >>= 1) {
      if (t < s) {
        const float d2 = sred[t+s]; const int i2 = sidx[t+s];
        if (d2 < sred[t] || (d2 == sred[t] && i2 < sidx[t])) { sred[t] = d2; sidx[t] = i2; }
      }
      __syncthreads();
    }
    const int bestj = sidx[0];
    __syncthreads();
    const float zq  = cb[(size_t)bestj * OO + t];
    const float ls  = LS[i];
    const float sig = 1.0f / (1.0f + expf(-ls));
    acc = fmaf(sig, zq, acc);
    rr[t] -= zq;
    __syncthreads();
  }
  OUT[b*OO + t] = acc;
}

// ---------------- host launch ----------------
extern "C" void kernel_launch(void* const* d_in, const int* in_sizes, int n_in,
                              void* d_out, int out_size, void* d_ws, size_t ws_size,
                              hipStream_t stream) {
  const float* x       = (const float*)d_in[0];
  const float* w_in    = (const float*)d_in[1];
  const float* b_in    = (const float*)d_in[2];
  const float* pos     = (const float*)d_in[3];
  const float* ln1_g   = (const float*)d_in[4];
  const float* ln1_b   = (const float*)d_in[5];
  const float* qkv_w   = (const float*)d_in[6];
  const float* qkv_b   = (const float*)d_in[7];
  const float* proj_w  = (const float*)d_in[8];
  const float* proj_b  = (const float*)d_in[9];
  const float* ln2_g   = (const float*)d_in[10];
  const float* ln2_b   = (const float*)d_in[11];
  const float* ff1_w   = (const float*)d_in[12];
  const float* ff1_b   = (const float*)d_in[13];
  const float* ff2_w   = (const float*)d_in[14];
  const float* ff2_b   = (const float*)d_in[15];
  const float* lnf_g   = (const float*)d_in[16];
  const float* lnf_b   = (const float*)d_in[17];
  const float* out1_w  = (const float*)d_in[18];
  const float* out1_b  = (const float*)d_in[19];
  const float* out2_w  = (const float*)d_in[20];
  const float* out2_b  = (const float*)d_in[21];
  const float* codebooks    = (const float*)d_in[22];
  const float* layer_scales = (const float*)d_in[23];

  float* ws  = (float*)d_ws;
  const size_t avail_f = ws_size / sizeof(float);
  const dim3 blk(256);

  const size_t f_h   = (size_t)NTOK * DD;
  const size_t f_ap  = (size_t)NTOK * DD;
  const size_t f_wt  = (size_t)FFD * DD;

  float* h = ws;
  size_t off = f_h;
  unsigned short* ahi = (unsigned short*)(ws + off);
  unsigned short* alo = ahi + (size_t)NTOK * DD;
  off += f_ap;
  unsigned short* wth = (unsigned short*)(ws + off);
  unsigned short* wtl = wth + (size_t)FFD * DD;
  off += f_wt;
  float* hl = ws + off;           off += (size_t)BB * DD;
  float* z1 = ws + off;           off += (size_t)BB * DD;
  float* zz = ws + off;           off += (size_t)BB * OO + 16;
  float* big = ws + off;
  const size_t big_f_mfma = (avail_f > off) ? (avail_f - off) : 0;

  const size_t qkv_row_f = (size_t)TT * 3 * DD;
  const bool use_mfma = big_f_mfma >= qkv_row_f;

  if (use_mfma) {
    int nbc = (int)(big_f_mfma / qkv_row_f);
    if (nbc < 1) nbc = 1;
    if (nbc > BB) nbc = BB;
    int mc = (int)((big_f_mfma / FFD) / 128) * 128;
    if (mc < 128) mc = 128;
    if (mc > NTOK) mc = NTOK;
    unsigned short* bighi = (unsigned short*)big;
    unsigned short* biglo = bighi + (size_t)mc * FFD;

    gemm_k<MODE_STORE><<<dim3(DD/128, NTOK/128), blk, 0, stream>>>(x, w_in, b_in, h, NTOK, DD, CC);
    addpos_k<<<NTOK, blk, 0, stream>>>(h, pos);

    for (int l = 0; l < LL; ++l) {
      ln_k<true><<<NTOK, blk, 0, stream>>>(h, DD, nullptr, ahi, alo, ln1_g + l*DD, ln1_b + l*DD);
      wsplit_k<<<dim3(3*DD/64, DD/64), blk, 0, stream>>>(qkv_w + (size_t)l*DD*3*DD, wth, wtl, DD, 3*DD);
      for (int b0 = 0; b0 < BB; b0 += nbc) {
        const int nb = (b0 + nbc <= BB) ? nbc : (BB - b0);
        const int Mq = nb * TT;
        gemm_mfma_k<GM_STORE><<<dim3(3*DD/128, Mq/128), blk, 0, stream>>>(
            ahi + (size_t)b0*TT*DD, alo + (size_t)b0*TT*DD, DD,
            wth, wtl, DD, qkv_b + (size_t)l*3*DD,
            big, nullptr, nullptr, 3*DD, Mq, 3*DD, DD);
        attn_mfma_k<<<dim3(TT/64, nb*HH_), blk, 0, stream>>>(
            big, ahi + (size_t)b0*TT*DD, alo + (size_t)b0*TT*DD);
      }
      wsplit_k<<<dim3(DD/64, DD/64), blk, 0, stream>>>(proj_w + (size_t)l*DD*DD, wth, wtl, DD, DD);
      gemm_mfma_k<GM_ADD><<<dim3(DD/128, NTOK/128), blk, 0, stream>>>(
          ahi, alo, DD, wth, wtl, DD, proj_b + (size_t)l*DD,
          h, nullptr, nullptr, DD, NTOK, DD, DD);
      ln_k<true><<<NTOK, blk, 0, stream>>>(h, DD, nullptr, ahi, alo, ln2_g + l*DD, ln2_b + l*DD);
      wsplit_k<<<dim3(FFD/64, DD/64), blk, 0, stream>>>(ff1_w + (size_t)l*DD*FFD, wth, wtl, DD, FFD);
      for (int r0 = 0; r0 < NTOK; r0 += mc) {
        const int mr = (r0 + mc <= NTOK) ? mc : (NTOK - r0);
        gemm_mfma_k<GM_GELU_SPLIT><<<dim3(FFD/128, mr/128), blk, 0, stream>>>(
            ahi + (size_t)r0*DD, alo + (size_t)r0*DD, DD,
            wth, wtl, DD, ff1_b + (size_t)l*FFD,
            nullptr, bighi, biglo, FFD, mr, FFD, DD);
        wsplit_k<<<dim3(DD/64, FFD/64), blk, 0, stream>>>(ff2_w + (size_t)l*FFD*DD, wth, wtl, FFD, DD);
        gemm_mfma_k<GM_ADD><<<dim3(DD/128, mr/128), blk, 0, stream>>>(
            bighi, biglo, FFD, wth, wtl, FFD, ff2_b + (size_t)l*DD,
            h + (size_t)r0*DD, nullptr, nullptr, DD, mr, DD, FFD);
        if (r0 + mc < NTOK)
          wsplit_k<<<dim3(FFD/64, DD/64), blk, 0, stream>>>(ff1_w + (size_t)l*DD*FFD, wth, wtl, DD, FFD);
      }
    }

    ln_k<false><<<BB, blk, 0, stream>>>(h + (size_t)(TT-1)*DD, (size_t)TT*DD, hl, nullptr, nullptr, lnf_g, lnf_b);
    gemm_k<MODE_GELU><<<dim3(DD/128, 1), blk, 0, stream>>>(hl, out1_w, out1_b, z1, BB, DD, DD);
    gemm_k<MODE_STORE><<<dim3(OO/128, 1), blk, 0, stream>>>(z1, out2_w, out2_b, zz, BB, OO, DD);
    rvq_k<<<BB, blk, 0, stream>>>(zz, codebooks, layer_scales, (float*)d_out);
    return;
  }

  // ---------------- fallback: pure fp32 path ----------------
  {
    float* a   = ws + f_h;
    float* hl2 = a + f_ap;
    float* z12 = hl2 + (size_t)BB * DD;
    float* zz2 = z12 + (size_t)BB * DD;
    float* big2 = zz2 + (size_t)BB * OO;
    const size_t base_f = (size_t)(big2 - ws);
    const size_t big_f = (avail_f > base_f) ? (avail_f - base_f) : 0;
    int nbc = (int)(big_f / qkv_row_f);
    if (nbc < 1) nbc = 1;
    if (nbc > BB) nbc = BB;
    int mc = (int)((big_f / FFD) / 128) * 128;
    if (mc < 128) mc = 128;
    if (mc > NTOK) mc = NTOK;

    gemm_k<MODE_STORE><<<dim3(DD/128, NTOK/128), blk, 0, stream>>>(x, w_in, b_in, h, NTOK, DD, CC);
    addpos_k<<<NTOK, blk, 0, stream>>>(h, pos);
    for (int l = 0; l < LL; ++l) {
      ln_k<false><<<NTOK, blk, 0, stream>>>(h, DD, a, nullptr, nullptr, ln1_g + l*DD, ln1_b + l*DD);
      for (int b0 = 0; b0 < BB; b0 += nbc) {
        const int nb = (b0 + nbc <= BB) ? nbc : (BB - b0);
        const int Mq = nb * TT;
        gemm_k<MODE_STORE><<<dim3((3*DD)/128, Mq/128), blk, 0, stream>>>(
            a + (size_t)b0*TT*DD, qkv_w + (size_t)l*DD*3*DD, qkv_b + (size_t)l*3*DD,
            big2, Mq, 3*DD, DD);
        attn_k<false><<<dim3(TT/64, nb*HH_), blk, 0, stream>>>(big2, a + (size_t)b0*TT*DD, nullptr, nullptr);
      }
      gemm_k<MODE_ADD><<<dim3(DD/128, NTOK/128), blk, 0, stream>>>(
          a, proj_w + (size_t)l*DD*DD, proj_b + (size_t)l*DD, h, NTOK, DD, DD);
      ln_k<false><<<NTOK, blk, 0, stream>>>(h, DD, a, nullptr, nullptr, ln2_g + l*DD, ln2_b + l*DD);
      for (int r0 = 0; r0 < NTOK; r0 += mc) {
        const int mr = (r0 + mc <= NTOK) ? mc : (NTOK - r0);
        gemm_k<MODE_GELU><<<dim3(FFD/128, mr/128), blk, 0, stream>>>(
            a + (size_t)r0*DD, ff1_w + (size_t)l*DD*FFD, ff1_b + (size_t)l*FFD,
            big2, mr, FFD, DD);
        gemm_k<MODE_ADD><<<dim3(DD/128, mr/128), blk, 0, stream>>>(
            big2, ff2_w + (size_t)l*FFD*DD, ff2_b + (size_t)l*DD, h + (size_t)r0*DD, mr, DD, FFD);
      }
    }
    ln_k<false><<<BB, blk, 0, stream>>>(h + (size_t)(TT-1)*DD, (size_t)TT*DD, hl2, nullptr, nullptr, lnf_g, lnf_b);
    gemm_k<MODE_GELU><<<dim3(DD/128, 1), blk, 0, stream>>>(hl2, out1_w, out1_b, z12, BB, DD, DD);
    gemm_k<MODE_STORE><<<dim3(OO/128, 1), blk, 0, stream>>>(z12, out2_w, out2_b, zz2, BB, OO, DD);
    rvq_k<<<BB, blk, 0, stream>>>(zz2, codebooks, layer_scales, (float*)d_out);
  }
}